// Round 18
// baseline (199.680 us; speedup 1.0000x reference)
//
#include <hip/hip_runtime.h>
#include <stdint.h>

#define NN 100000     // nodes
#define NE 640000     // edges
#define DD 128        // features
#define BN_EPS 1e-5f
#define NB 391        // scan blocks: 391*256 = 100096 >= NN
#define NROWPAD 100096
#define NTILE 782     // 128-row tiles: 782*128 = 100096
#define GGRID 512     // gemm grid (2 blocks/CU)

typedef __attribute__((ext_vector_type(8)))  short bf16x8;
typedef __attribute__((ext_vector_type(4)))  float f32x4;

static __device__ __forceinline__ float bf2f(unsigned short s) {
  return __uint_as_float(((unsigned)s) << 16);
}
static __device__ __forceinline__ unsigned short f2bf(float f) {
  unsigned u = __float_as_uint(f);
  u += 0x7FFFu + ((u >> 16) & 1u);   // RNE
  return (unsigned short)(u >> 16);
}

// LAYOUT:
//   magg[NROWPAD][128] bf16 : mean-agg; gemm overwrites in-place w/ out_pre.
//   xbf [NROWPAD][128] bf16 : relu(x), compact gather source.
//   cur (400KB) ALIASES magg rows 0..1563: live only k_scan->k_fill, and
//       k_agg (which writes those magg rows) runs strictly after k_fill.
//       k_setup touches only magg's pad-row tail (+25.6MB). Single-writer-
//       then-reader across launch boundaries -> race-free.

// ---- 0. zero deg ---------------------------------------------------------
__global__ __launch_bounds__(1024) void k_zero(int* __restrict__ deg)
{
  int i = blockIdx.x * 1024 + threadIdx.x;
  if (i < NROWPAD) deg[i] = 0;
}

// ---- 1. merged setup, INTERLEAVED roles ----------------------------------
// hist blocks (640K device-scope atomics) are every 4th block (b&3==3 ->
// exactly 2500), spread uniformly so atomics overlap the prep streaming
// from t=0 (worth ~8us vs sequential role ranges).
__global__ __launch_bounds__(256) void k_setup(
    const float* __restrict__ x,
    const float* __restrict__ Wl, const float* __restrict__ Wr,
    const int* __restrict__ ei,
    unsigned short* __restrict__ xbf, unsigned short* __restrict__ magg,
    unsigned short* __restrict__ wbf, int* __restrict__ deg)
{
  int b = blockIdx.x;                   // grid 10000
  if ((b & 3) == 3) {
    int e = (b >> 2) * 256 + threadIdx.x;
    if (e < NE) atomicAdd(deg + ei[NE + e], 1);
    return;
  }
  int rank = b - (b >> 2);              // 0..7499
  if (rank < 6256) {
    // xbf[row][j] = bf16(relu(x[row][j])); pad rows zero xbf AND magg
    int i = rank * 256 + threadIdx.x;   // 0 .. NROWPAD*16-1
    int row = i >> 4, cj = i & 15;
    if (row < NN) {
      const float* xp = x + (long)row * DD + cj * 8;
      float tmp[8];
      *(float4*)(tmp)     = *(const float4*)(xp);
      *(float4*)(tmp + 4) = *(const float4*)(xp + 4);
      bf16x8 o;
#pragma unroll
      for (int e = 0; e < 8; ++e) o[e] = (short)f2bf(fmaxf(tmp[e], 0.f));
      *(bf16x8*)(xbf + (long)row * DD + cj * 8) = o;
    } else {                            // rows NN..NROWPAD-1: zero fill
      bf16x8 z = {};
      *(bf16x8*)(xbf  + (long)row * DD + cj * 8) = z;
      *(bf16x8*)(magg + (long)row * DD + cj * 8) = z;
    }
  } else if (rank < 6384) {
    // wbf[col][0..255] = [Wl[col][:] | Wr[col][:]] as bf16
    int i = (rank - 6256) * 256 + threadIdx.x;
    int col = i >> 8, k = i & 255;
    float v = (k < DD) ? Wl[col * DD + k] : Wr[col * DD + (k - DD)];
    wbf[i] = f2bf(v);
  }
}

// ---- 2. merged exclusive scan, RACE-FREE ---------------------------------
// R14/R15 crash root cause: merged scan wrote cursors INTO deg while other
// blocks strided-read deg for their prefixes. Fix: deg is STRICTLY READ-
// ONLY here; boundaries -> offs, cursors -> separate cur buffer. No block
// reads anything another block writes -> dispatch-order-independent.
__global__ __launch_bounds__(256) void k_scan(const int* __restrict__ deg,
                                              int* __restrict__ offs,
                                              int* __restrict__ cur)
{
  __shared__ int sc[256];
  __shared__ int pre[256];
  int t = threadIdx.x;
  int lim = blockIdx.x * 256;
  int p = 0;
  for (int j = t; j < lim; j += 256) p += deg[j];    // read-only prefix
  pre[t] = p;
  __syncthreads();
  for (int s = 128; s > 0; s >>= 1) {
    if (t < s) pre[t] += pre[t + s];
    __syncthreads();
  }
  int boff = pre[0];
  __syncthreads();
  int i = lim + t;
  int v = deg[i];
  sc[t] = v;
  __syncthreads();
  for (int s = 1; s < 256; s <<= 1) {
    int add = (t >= s) ? sc[t - s] : 0;
    __syncthreads();
    sc[t] += add;
    __syncthreads();
  }
  int excl = sc[t] - v + boff;
  offs[i] = excl;
  cur[i]  = excl;
}

// ---- 3. fill CSR ---------------------------------------------------------
__global__ __launch_bounds__(256) void k_fill(const int* __restrict__ ei,
                                              int* __restrict__ cur,
                                              int* __restrict__ esrc)
{
  int e = blockIdx.x * 256 + threadIdx.x;
  if (e >= NE) return;
  int pos = atomicAdd(cur + ei[NE + e], 1);
  esrc[pos] = ei[e];
}

// ---- 4. gather-aggregate: magg[dst] = bf16(mean(xbf[src])) ---------------
// R7/R10-proven 4x16 layout: 4 quarter-waves of 16 lanes own edge stream
// i*4+q; one wave-wide load covers 4 DIFFERENT edges' compact 256B rows
// (4x MLP; 8x with unroll 2). R9's 8x8 variant went VALU-bound on the
// tripled reduce tail -- do not repeat. Lanes past the edge count hold
// src=NN (zeroed pad row) -> adds 0, branch-free.
__global__ __launch_bounds__(256) void k_agg(const int* __restrict__ offs,
                                             const int* __restrict__ esrc,
                                             const unsigned short* __restrict__ xbf,
                                             unsigned short* __restrict__ magg)
{
  int dst = blockIdx.x * 4 + (threadIdx.x >> 6);
  if (dst >= NN) return;
  int lane = threadIdx.x & 63;
  int q  = lane >> 4;        // quarter-wave 0..3 = edge slot
  int fl = lane & 15;        // feature lane: feats fl*8 .. fl*8+7
  int off = offs[dst], end = offs[dst + 1];
  int deg = end - off;
  float acc[8];
#pragma unroll
  for (int e = 0; e < 8; ++e) acc[e] = 0.f;

  for (int base = off; base < end; base += 64) {
    int m = end - base; if (m > 64) m = 64;
    int mysrc = (base + lane < end) ? esrc[base + lane] : NN;  // NN = zero pad row
    int iters = (m + 3) >> 2;
#pragma unroll 2
    for (int i = 0; i < iters; ++i) {
      int src = __shfl(mysrc, i * 4 + q);    // i*4+q <= 63; >=m lanes hold NN
      bf16x8 w = *(const bf16x8*)(xbf + (long)src * DD + fl * 8);
#pragma unroll
      for (int e = 0; e < 8; ++e) acc[e] += bf2f((unsigned short)w[e]);
    }
  }

#pragma unroll
  for (int e = 0; e < 8; ++e) {
    acc[e] += __shfl_xor(acc[e], 16);
    acc[e] += __shfl_xor(acc[e], 32);
  }
  if (q == 0) {
    float rinv = (deg > 0) ? 1.0f / (float)deg : 0.f;
    bf16x8 o;
#pragma unroll
    for (int e = 0; e < 8; ++e) o[e] = (short)f2bf(acc[e] * rinv);
    *(bf16x8*)(magg + (long)dst * DD + fl * 8) = o;
  }
}

// ======== streaming GEMM (single pass) ====================================
// Block: 512 thr = 8 waves. B (= wbf, 128x256 bf16 = 64KB) staged once in
// LDS with XOR-swizzle byte ^= (col&7)<<4. Each wave owns a 16-row strip
// per tile; A-fragments load DIRECTLY from global: K 0..127 from magg row,
// K 128..255 from xbf row. No barriers in the tile loop.
// REGISTER BUDGET: (512,2) caps VGPR at 128 (2 blocks/CU, LDS-bound); per-
// ks A-load unroll 4, <=4 frags in flight -> no spills.
// LDS BUDGET: blds is EXACTLY 64KB -- do not add __shared__ variables.
#define GEMM_STAGE_B() \
  _Pragma("unroll") \
  for (int j = 0; j < 8; ++j) { \
    int id = j * 512 + t, col = id >> 5, seg = id & 31; \
    uint4 v = *(const uint4*)(wbf + col * 256 + seg * 8); \
    int byte = (col << 9) + (seg << 4); byte ^= (col & 7) << 4; \
    *(uint4*)((char*)blds + byte) = v; \
  } \
  __syncthreads();

#define GEMM_TILE_COMPUTE(rb) \
  { const unsigned short* ap0 = magg + (long)((rb) + c15) * DD + kg * 8; \
    const unsigned short* ap1 = xbf  + (long)((rb) + c15) * DD + kg * 8; \
    _Pragma("unroll 4") \
    for (int ks = 0; ks < 8; ++ks) { \
      bf16x8 a = (ks < 4) ? *(const bf16x8*)(ap0 + ks * 32) \
                          : *(const bf16x8*)(ap1 + (ks - 4) * 32); \
      _Pragma("unroll") \
      for (int ct = 0; ct < 8; ++ct) { \
        int byte = ((ct * 16 + c15) << 9) + (ks << 6) + (kg << 4); \
        byte ^= (c15 & 7) << 4; \
        bf16x8 b = *(const bf16x8*)((const char*)blds + byte); \
        acc[ct] = __builtin_amdgcn_mfma_f32_16x16x32_bf16(a, b, acc[ct], 0, 0, 0); \
      } \
    } }

// ---- 5. GEMM: raw column stats + bf16 out_pre OVER magg ------------------
// Pad rows are zeroed in xbf+magg -> contribute 0 to stats, store 0s.
__global__ __launch_bounds__(512, 2) void k_gemm1(
    unsigned short* __restrict__ magg,
    const unsigned short* __restrict__ xbf,
    const unsigned short* __restrict__ wbf,
    float* __restrict__ partials)
{
  __shared__ __align__(16) unsigned short blds[32768];   // 64KB B (FULL)
  const int t = threadIdx.x;
  const int lane = t & 63, wv = t >> 6;
  const int c15 = lane & 15, kg = lane >> 4;

  GEMM_STAGE_B();

  float sS[8], sQ[8];
#pragma unroll
  for (int ct = 0; ct < 8; ++ct) { sS[ct] = 0.f; sQ[ct] = 0.f; }

  for (int tile = blockIdx.x; tile < NTILE; tile += GGRID) {
    int rb = tile * 128 + wv * 16;
    f32x4 acc[8];
#pragma unroll
    for (int ct = 0; ct < 8; ++ct) acc[ct] = (f32x4){0.f, 0.f, 0.f, 0.f};
    GEMM_TILE_COMPUTE(rb);
#pragma unroll
    for (int ct = 0; ct < 8; ++ct) {
      int col = ct * 16 + c15;
#pragma unroll
      for (int r = 0; r < 4; ++r) {
        float v = acc[ct][r];
        sS[ct] += v;
        sQ[ct] += v * v;
        magg[(long)(rb + kg * 4 + r) * DD + col] = f2bf(v);  // out_pre bf16
      }
    }
  }

  // block-level reduce through LDS (B no longer needed)
  __syncthreads();
  float* slds = (float*)blds;   // [8 waves][256] = 8KB
#pragma unroll
  for (int ct = 0; ct < 8; ++ct) {
    float s = sS[ct], q = sQ[ct];
    s += __shfl_xor(s, 16); q += __shfl_xor(q, 16);
    s += __shfl_xor(s, 32); q += __shfl_xor(q, 32);
    if (lane < 16) {
      slds[wv * 256 + ct * 16 + lane] = s;
      slds[wv * 256 + 128 + ct * 16 + lane] = q;
    }
  }
  __syncthreads();
  if (t < 256) {
    float a = 0.f;
#pragma unroll
    for (int w = 0; w < 8; ++w) a += slds[w * 256 + t];
    partials[blockIdx.x * 256 + t] = a;
  }
}

// ---- 6. reduce partials; fold bias; emit sc / (bias*sc + shift) ----------
__global__ __launch_bounds__(1024) void k_stats(
    const float* __restrict__ partials, const float* __restrict__ bl,
    const float* __restrict__ gamma, const float* __restrict__ beta,
    float* __restrict__ ss)
{
  __shared__ float red[4][256];
  int t = threadIdx.x & 255, g = threadIdx.x >> 8;
  float a = 0.f;
#pragma unroll 8
  for (int blk = g; blk < GGRID; blk += 4) a += partials[blk * 256 + t];
  red[g][t] = a;
  __syncthreads();
  if (threadIdx.x < 256)
    red[0][t] = red[0][t] + red[1][t] + red[2][t] + red[3][t];
  __syncthreads();
  if (threadIdx.x < 128) {
    float Sr = red[0][t], Qr = red[0][128 + t];
    float b  = bl[t];
    float S  = Sr + (float)NN * b;                    // fold bias into stats
    float Q  = Qr + 2.f * b * Sr + (float)NN * b * b;
    float mu  = S / (float)NN;
    float var = Q / (float)NN - mu * mu;              // biased variance
    float rsig = rsqrtf(var + BN_EPS);
    float sc  = gamma[t] * rsig;
    float sh2 = beta[t] - mu * sc;
    ss[t]       = sc;
    ss[128 + t] = b * sc + sh2;                       // bias folded into shift
  }
}

// ---- 7. streaming BN affine: out = sc * out_pre(bf16) + shift ------------
// Grid geometry MATCHES k_gemm1 (512 blocks, tile = bid + 512-stride) so
// block b re-reads the out_pre rows gemm block b wrote (XCD-L2 locality
// heuristic; speed only, never correctness).
__global__ __launch_bounds__(512) void k_norm(
    const unsigned short* __restrict__ magg,
    const float* __restrict__ ss,
    float* __restrict__ out)
{
  __shared__ float sc[128], sh[128];
  if (threadIdx.x < 128) {
    sc[threadIdx.x] = ss[threadIdx.x];
    sh[threadIdx.x] = ss[128 + threadIdx.x];
  }
  __syncthreads();
  for (int tile = blockIdx.x; tile < NTILE; tile += GGRID) {
    long tb = (long)tile * 128;
    for (int i = threadIdx.x; i < 2048; i += 512) {   // 128 rows x 16 chunks
      long row = tb + (i >> 4);
      if (row >= NN) continue;
      int c0 = (i & 15) * 8;
      bf16x8 v = *(const bf16x8*)(magg + row * DD + c0);
      float4 o0, o1;
      o0.x = fmaf(bf2f((unsigned short)v[0]), sc[c0 + 0], sh[c0 + 0]);
      o0.y = fmaf(bf2f((unsigned short)v[1]), sc[c0 + 1], sh[c0 + 1]);
      o0.z = fmaf(bf2f((unsigned short)v[2]), sc[c0 + 2], sh[c0 + 2]);
      o0.w = fmaf(bf2f((unsigned short)v[3]), sc[c0 + 3], sh[c0 + 3]);
      o1.x = fmaf(bf2f((unsigned short)v[4]), sc[c0 + 4], sh[c0 + 4]);
      o1.y = fmaf(bf2f((unsigned short)v[5]), sc[c0 + 5], sh[c0 + 5]);
      o1.z = fmaf(bf2f((unsigned short)v[6]), sc[c0 + 6], sh[c0 + 6]);
      o1.w = fmaf(bf2f((unsigned short)v[7]), sc[c0 + 7], sh[c0 + 7]);
      *(float4*)(out + row * DD + c0)     = o0;
      *(float4*)(out + row * DD + c0 + 4) = o1;
    }
  }
}

extern "C" void kernel_launch(void* const* d_in, const int* in_sizes, int n_in,
                              void* d_out, int out_size, void* d_ws, size_t ws_size,
                              hipStream_t stream)
{
  const float* x     = (const float*)d_in[0];
  // d_in[1] = edge_attr — unused by the reference
  const float* Wl    = (const float*)d_in[2];
  const float* bl    = (const float*)d_in[3];
  const float* Wr    = (const float*)d_in[4];
  const float* gamma = (const float*)d_in[5];
  const float* beta  = (const float*)d_in[6];
  const int*   ei    = (const int*)d_in[7];
  float* out = (float*)d_out;

  char* ws = (char*)d_ws;
  unsigned short* magg = (unsigned short*)(ws);            // 100096*128*2 = 25,624,576
  unsigned short* xbf  = (unsigned short*)(ws + 25624576); // 25,624,576 -> 51,249,152
  int*   esrc  = (int*)(ws + 51249152);                    //  2,560,000 -> 53,809,152
  int*   deg   = (int*)(ws + 53809152);                    //    400,384 -> 54,209,536
  int*   offs  = (int*)(ws + 54209536);                    //    400,384 -> 54,609,920
  unsigned short* wbf = (unsigned short*)(ws + 54609920);  //     65,536 -> 54,675,456
  // ALIASES (stream-ordered single-writer-then-reader, see layout note):
  int*   cur      = (int*)ws;       // magg rows 0..1563; live k_scan->k_fill only
  float* partials = (float*)esrc;   // gemm1 partials [512][256] f32; esrc dead after k_agg
  float* ssbuf    = (float*)deg;    // 256 f32; deg dead after k_scan
  (void)ws_size; (void)in_sizes; (void)n_in; (void)out_size;

  k_zero  <<<98,   1024, 0, stream>>>(deg);
  k_setup <<<10000, 256, 0, stream>>>(x, Wl, Wr, ei, xbf, magg, wbf, deg);
  k_scan  <<<NB,    256, 0, stream>>>(deg, offs, cur);
  k_fill  <<<2500,  256, 0, stream>>>(ei, cur, esrc);
  k_agg   <<<25000, 256, 0, stream>>>(offs, esrc, xbf, magg);
  k_gemm1 <<<GGRID, 512, 0, stream>>>(magg, xbf, wbf, partials);
  k_stats <<<1,    1024, 0, stream>>>(partials, bl, gamma, beta, ssbuf);
  k_norm  <<<GGRID, 512, 0, stream>>>(magg, ssbuf, out);
}

// Round 19
// 152.939 us; speedup vs baseline: 1.3056x; 1.3056x over previous
//
#include <hip/hip_runtime.h>
#include <stdint.h>

#define NN 100000     // nodes
#define NE 640000     // edges
#define DD 128        // features
#define BN_EPS 1e-5f
#define NB 391        // scan blocks: 391*256 = 100096 >= NN
#define NROWPAD 100096
#define NTILE 782     // 128-row tiles: 782*128 = 100096
#define GGRID 512     // gemm grid (2 blocks/CU)

typedef __attribute__((ext_vector_type(8)))  short bf16x8;
typedef __attribute__((ext_vector_type(4)))  float f32x4;

static __device__ __forceinline__ float bf2f(unsigned short s) {
  return __uint_as_float(((unsigned)s) << 16);
}
static __device__ __forceinline__ unsigned short f2bf(float f) {
  unsigned u = __float_as_uint(f);
  u += 0x7FFFu + ((u >> 16) & 1u);   // RNE
  return (unsigned short)(u >> 16);
}

// LAYOUT (R16/R17 proven):
//   magg[NROWPAD][128] bf16 : mean-agg; gemm overwrites in-place w/ out_pre.
//   xbf [NROWPAD][128] bf16 : relu(x), compact gather source.
// SCAN LEDGER (R14/R15/R18): the scan stays TWO launches. Merged variants
// either race (cursor writes into deg while others prefix-read it -> OOB
// crash) or go latency-bound (prefix over 400KB deg at 1KB stride = 54us,
// R18). The bsum materialization is what makes the prefix both cheap
// (391 L1-resident ints) and race-free. Do not re-merge.

// ---- 0. zero deg ---------------------------------------------------------
__global__ __launch_bounds__(1024) void k_zero(int* __restrict__ deg)
{
  int i = blockIdx.x * 1024 + threadIdx.x;
  if (i < NROWPAD) deg[i] = 0;
}

// ---- 1. merged setup, INTERLEAVED roles ----------------------------------
// hist blocks (640K device-scope atomics) are every 4th block (b&3==3 ->
// exactly 2500), spread uniformly so atomics overlap the prep streaming
// from t=0 (worth ~8us vs sequential role ranges).
__global__ __launch_bounds__(256) void k_setup(
    const float* __restrict__ x,
    const float* __restrict__ Wl, const float* __restrict__ Wr,
    const int* __restrict__ ei,
    unsigned short* __restrict__ xbf, unsigned short* __restrict__ magg,
    unsigned short* __restrict__ wbf, int* __restrict__ deg)
{
  int b = blockIdx.x;                   // grid 10000
  if ((b & 3) == 3) {
    int e = (b >> 2) * 256 + threadIdx.x;
    if (e < NE) atomicAdd(deg + ei[NE + e], 1);
    return;
  }
  int rank = b - (b >> 2);              // 0..7499
  if (rank < 6256) {
    // xbf[row][j] = bf16(relu(x[row][j])); pad rows zero xbf AND magg
    int i = rank * 256 + threadIdx.x;   // 0 .. NROWPAD*16-1
    int row = i >> 4, cj = i & 15;
    if (row < NN) {
      const float* xp = x + (long)row * DD + cj * 8;
      float tmp[8];
      *(float4*)(tmp)     = *(const float4*)(xp);
      *(float4*)(tmp + 4) = *(const float4*)(xp + 4);
      bf16x8 o;
#pragma unroll
      for (int e = 0; e < 8; ++e) o[e] = (short)f2bf(fmaxf(tmp[e], 0.f));
      *(bf16x8*)(xbf + (long)row * DD + cj * 8) = o;
    } else {                            // rows NN..NROWPAD-1: zero fill
      bf16x8 z = {};
      *(bf16x8*)(xbf  + (long)row * DD + cj * 8) = z;
      *(bf16x8*)(magg + (long)row * DD + cj * 8) = z;
    }
  } else if (rank < 6384) {
    // wbf[col][0..255] = [Wl[col][:] | Wr[col][:]] as bf16
    int i = (rank - 6256) * 256 + threadIdx.x;
    int col = i >> 8, k = i & 255;
    float v = (k < DD) ? Wl[col * DD + k] : Wr[col * DD + (k - DD)];
    wbf[i] = f2bf(v);
  }
}

// ---- 2a. block sums ------------------------------------------------------
__global__ __launch_bounds__(256) void k_scan1(const int* __restrict__ deg,
                                               int* __restrict__ bsum)
{
  __shared__ int sc[256];
  int t = threadIdx.x;
  sc[t] = deg[blockIdx.x * 256 + t];
  __syncthreads();
  for (int s = 128; s > 0; s >>= 1) {
    if (t < s) sc[t] += sc[t + s];
    __syncthreads();
  }
  if (t == 0) bsum[blockIdx.x] = sc[0];
}

// ---- 2b. per-element exclusive scan (self-computes block prefix from
// STABLE bsum; reads/writes only its OWN deg block -> race-free) ----------
__global__ __launch_bounds__(256) void k_scan3(int* __restrict__ deg,
                                               const int* __restrict__ bsum,
                                               int* __restrict__ offs)
{
  __shared__ int sc[256];
  __shared__ int pre[256];
  int t = threadIdx.x;
  int p = 0;
  for (int j = t; j < blockIdx.x; j += 256) p += bsum[j];
  pre[t] = p;
  __syncthreads();
  for (int s = 128; s > 0; s >>= 1) {
    if (t < s) pre[t] += pre[t + s];
    __syncthreads();
  }
  int boff = pre[0];
  __syncthreads();
  int i = blockIdx.x * 256 + t;
  int v = deg[i];
  sc[t] = v;
  __syncthreads();
  for (int s = 1; s < 256; s <<= 1) {
    int add = (t >= s) ? sc[t - s] : 0;
    __syncthreads();
    sc[t] += add;
    __syncthreads();
  }
  int excl = sc[t] - v + boff;
  offs[i] = excl;
  deg[i]  = excl;     // deg becomes fill-cursor
}

// ---- 3. fill CSR ---------------------------------------------------------
__global__ __launch_bounds__(256) void k_fill(const int* __restrict__ ei,
                                              int* __restrict__ cursor,
                                              int* __restrict__ esrc)
{
  int e = blockIdx.x * 256 + threadIdx.x;
  if (e >= NE) return;
  int pos = atomicAdd(cursor + ei[NE + e], 1);
  esrc[pos] = ei[e];
}

// ---- 4. gather-aggregate: magg[dst] = bf16(mean(xbf[src])) ---------------
// R7/R10-proven 4x16 layout: 4 quarter-waves of 16 lanes own edge stream
// i*4+q; one wave-wide load covers 4 DIFFERENT edges' compact 256B rows
// (4x MLP; 8x with unroll 2). R9's 8x8 variant went VALU-bound on the
// tripled reduce tail -- do not repeat. Lanes past the edge count hold
// src=NN (zeroed pad row) -> adds 0, branch-free.
__global__ __launch_bounds__(256) void k_agg(const int* __restrict__ offs,
                                             const int* __restrict__ esrc,
                                             const unsigned short* __restrict__ xbf,
                                             unsigned short* __restrict__ magg)
{
  int dst = blockIdx.x * 4 + (threadIdx.x >> 6);
  if (dst >= NN) return;
  int lane = threadIdx.x & 63;
  int q  = lane >> 4;        // quarter-wave 0..3 = edge slot
  int fl = lane & 15;        // feature lane: feats fl*8 .. fl*8+7
  int off = offs[dst], end = offs[dst + 1];
  int deg = end - off;
  float acc[8];
#pragma unroll
  for (int e = 0; e < 8; ++e) acc[e] = 0.f;

  for (int base = off; base < end; base += 64) {
    int m = end - base; if (m > 64) m = 64;
    int mysrc = (base + lane < end) ? esrc[base + lane] : NN;  // NN = zero pad row
    int iters = (m + 3) >> 2;
#pragma unroll 2
    for (int i = 0; i < iters; ++i) {
      int src = __shfl(mysrc, i * 4 + q);    // i*4+q <= 63; >=m lanes hold NN
      bf16x8 w = *(const bf16x8*)(xbf + (long)src * DD + fl * 8);
#pragma unroll
      for (int e = 0; e < 8; ++e) acc[e] += bf2f((unsigned short)w[e]);
    }
  }

#pragma unroll
  for (int e = 0; e < 8; ++e) {
    acc[e] += __shfl_xor(acc[e], 16);
    acc[e] += __shfl_xor(acc[e], 32);
  }
  if (q == 0) {
    float rinv = (deg > 0) ? 1.0f / (float)deg : 0.f;
    bf16x8 o;
#pragma unroll
    for (int e = 0; e < 8; ++e) o[e] = (short)f2bf(acc[e] * rinv);
    *(bf16x8*)(magg + (long)dst * DD + fl * 8) = o;
  }
}

// ======== streaming GEMM (single pass) ====================================
// Block: 512 thr = 8 waves. B (= wbf, 128x256 bf16 = 64KB) staged once in
// LDS with XOR-swizzle byte ^= (col&7)<<4. Each wave owns a 16-row strip
// per tile; A-fragments load DIRECTLY from global: K 0..127 from magg row,
// K 128..255 from xbf row. No barriers in the tile loop.
// REGISTER BUDGET: (512,2) caps VGPR at 128 (2 blocks/CU, LDS-bound); per-
// ks A-load unroll 4, <=4 frags in flight -> no spills.
// LDS BUDGET: blds is EXACTLY 64KB -- do not add __shared__ variables.
#define GEMM_STAGE_B() \
  _Pragma("unroll") \
  for (int j = 0; j < 8; ++j) { \
    int id = j * 512 + t, col = id >> 5, seg = id & 31; \
    uint4 v = *(const uint4*)(wbf + col * 256 + seg * 8); \
    int byte = (col << 9) + (seg << 4); byte ^= (col & 7) << 4; \
    *(uint4*)((char*)blds + byte) = v; \
  } \
  __syncthreads();

#define GEMM_TILE_COMPUTE(rb) \
  { const unsigned short* ap0 = magg + (long)((rb) + c15) * DD + kg * 8; \
    const unsigned short* ap1 = xbf  + (long)((rb) + c15) * DD + kg * 8; \
    _Pragma("unroll 4") \
    for (int ks = 0; ks < 8; ++ks) { \
      bf16x8 a = (ks < 4) ? *(const bf16x8*)(ap0 + ks * 32) \
                          : *(const bf16x8*)(ap1 + (ks - 4) * 32); \
      _Pragma("unroll") \
      for (int ct = 0; ct < 8; ++ct) { \
        int byte = ((ct * 16 + c15) << 9) + (ks << 6) + (kg << 4); \
        byte ^= (c15 & 7) << 4; \
        bf16x8 b = *(const bf16x8*)((const char*)blds + byte); \
        acc[ct] = __builtin_amdgcn_mfma_f32_16x16x32_bf16(a, b, acc[ct], 0, 0, 0); \
      } \
    } }

// ---- 5. GEMM: raw column stats + bf16 out_pre OVER magg ------------------
// Pad rows are zeroed in xbf+magg -> contribute 0 to stats, store 0s.
__global__ __launch_bounds__(512, 2) void k_gemm1(
    unsigned short* __restrict__ magg,
    const unsigned short* __restrict__ xbf,
    const unsigned short* __restrict__ wbf,
    float* __restrict__ partials)
{
  __shared__ __align__(16) unsigned short blds[32768];   // 64KB B (FULL)
  const int t = threadIdx.x;
  const int lane = t & 63, wv = t >> 6;
  const int c15 = lane & 15, kg = lane >> 4;

  GEMM_STAGE_B();

  float sS[8], sQ[8];
#pragma unroll
  for (int ct = 0; ct < 8; ++ct) { sS[ct] = 0.f; sQ[ct] = 0.f; }

  for (int tile = blockIdx.x; tile < NTILE; tile += GGRID) {
    int rb = tile * 128 + wv * 16;
    f32x4 acc[8];
#pragma unroll
    for (int ct = 0; ct < 8; ++ct) acc[ct] = (f32x4){0.f, 0.f, 0.f, 0.f};
    GEMM_TILE_COMPUTE(rb);
#pragma unroll
    for (int ct = 0; ct < 8; ++ct) {
      int col = ct * 16 + c15;
#pragma unroll
      for (int r = 0; r < 4; ++r) {
        float v = acc[ct][r];
        sS[ct] += v;
        sQ[ct] += v * v;
        magg[(long)(rb + kg * 4 + r) * DD + col] = f2bf(v);  // out_pre bf16
      }
    }
  }

  // block-level reduce through LDS (B no longer needed)
  __syncthreads();
  float* slds = (float*)blds;   // [8 waves][256] = 8KB
#pragma unroll
  for (int ct = 0; ct < 8; ++ct) {
    float s = sS[ct], q = sQ[ct];
    s += __shfl_xor(s, 16); q += __shfl_xor(q, 16);
    s += __shfl_xor(s, 32); q += __shfl_xor(q, 32);
    if (lane < 16) {
      slds[wv * 256 + ct * 16 + lane] = s;
      slds[wv * 256 + 128 + ct * 16 + lane] = q;
    }
  }
  __syncthreads();
  if (t < 256) {
    float a = 0.f;
#pragma unroll
    for (int w = 0; w < 8; ++w) a += slds[w * 256 + t];
    partials[blockIdx.x * 256 + t] = a;
  }
}

// ---- 6. reduce partials; fold bias; emit sc / (bias*sc + shift) ----------
__global__ __launch_bounds__(1024) void k_stats(
    const float* __restrict__ partials, const float* __restrict__ bl,
    const float* __restrict__ gamma, const float* __restrict__ beta,
    float* __restrict__ ss)
{
  __shared__ float red[4][256];
  int t = threadIdx.x & 255, g = threadIdx.x >> 8;
  float a = 0.f;
#pragma unroll 8
  for (int blk = g; blk < GGRID; blk += 4) a += partials[blk * 256 + t];
  red[g][t] = a;
  __syncthreads();
  if (threadIdx.x < 256)
    red[0][t] = red[0][t] + red[1][t] + red[2][t] + red[3][t];
  __syncthreads();
  if (threadIdx.x < 128) {
    float Sr = red[0][t], Qr = red[0][128 + t];
    float b  = bl[t];
    float S  = Sr + (float)NN * b;                    // fold bias into stats
    float Q  = Qr + 2.f * b * Sr + (float)NN * b * b;
    float mu  = S / (float)NN;
    float var = Q / (float)NN - mu * mu;              // biased variance
    float rsig = rsqrtf(var + BN_EPS);
    float sc  = gamma[t] * rsig;
    float sh2 = beta[t] - mu * sc;
    ss[t]       = sc;
    ss[128 + t] = b * sc + sh2;                       // bias folded into shift
  }
}

// ---- 7. streaming BN affine: out = sc * out_pre(bf16) + shift ------------
// Grid geometry MATCHES k_gemm1 (512 blocks, tile = bid + 512-stride) so
// block b re-reads the out_pre rows gemm block b wrote (XCD-L2 locality
// heuristic; speed only, never correctness).
__global__ __launch_bounds__(512) void k_norm(
    const unsigned short* __restrict__ magg,
    const float* __restrict__ ss,
    float* __restrict__ out)
{
  __shared__ float sc[128], sh[128];
  if (threadIdx.x < 128) {
    sc[threadIdx.x] = ss[threadIdx.x];
    sh[threadIdx.x] = ss[128 + threadIdx.x];
  }
  __syncthreads();
  for (int tile = blockIdx.x; tile < NTILE; tile += GGRID) {
    long tb = (long)tile * 128;
    for (int i = threadIdx.x; i < 2048; i += 512) {   // 128 rows x 16 chunks
      long row = tb + (i >> 4);
      if (row >= NN) continue;
      int c0 = (i & 15) * 8;
      bf16x8 v = *(const bf16x8*)(magg + row * DD + c0);
      float4 o0, o1;
      o0.x = fmaf(bf2f((unsigned short)v[0]), sc[c0 + 0], sh[c0 + 0]);
      o0.y = fmaf(bf2f((unsigned short)v[1]), sc[c0 + 1], sh[c0 + 1]);
      o0.z = fmaf(bf2f((unsigned short)v[2]), sc[c0 + 2], sh[c0 + 2]);
      o0.w = fmaf(bf2f((unsigned short)v[3]), sc[c0 + 3], sh[c0 + 3]);
      o1.x = fmaf(bf2f((unsigned short)v[4]), sc[c0 + 4], sh[c0 + 4]);
      o1.y = fmaf(bf2f((unsigned short)v[5]), sc[c0 + 5], sh[c0 + 5]);
      o1.z = fmaf(bf2f((unsigned short)v[6]), sc[c0 + 6], sh[c0 + 6]);
      o1.w = fmaf(bf2f((unsigned short)v[7]), sc[c0 + 7], sh[c0 + 7]);
      *(float4*)(out + row * DD + c0)     = o0;
      *(float4*)(out + row * DD + c0 + 4) = o1;
    }
  }
}

extern "C" void kernel_launch(void* const* d_in, const int* in_sizes, int n_in,
                              void* d_out, int out_size, void* d_ws, size_t ws_size,
                              hipStream_t stream)
{
  const float* x     = (const float*)d_in[0];
  // d_in[1] = edge_attr — unused by the reference
  const float* Wl    = (const float*)d_in[2];
  const float* bl    = (const float*)d_in[3];
  const float* Wr    = (const float*)d_in[4];
  const float* gamma = (const float*)d_in[5];
  const float* beta  = (const float*)d_in[6];
  const int*   ei    = (const int*)d_in[7];
  float* out = (float*)d_out;

  char* ws = (char*)d_ws;
  unsigned short* magg = (unsigned short*)(ws);            // 100096*128*2 = 25,624,576
  unsigned short* xbf  = (unsigned short*)(ws + 25624576); // 25,624,576 -> 51,249,152
  int*   esrc  = (int*)(ws + 51249152);                    //  2,560,000 -> 53,809,152
  int*   deg   = (int*)(ws + 53809152);                    //    400,384 -> 54,209,536
  int*   offs  = (int*)(ws + 54209536);                    //    400,384 -> 54,609,920
  int*   bsum  = (int*)(ws + 54609920);                    //      2,048 -> 54,611,968
  unsigned short* wbf = (unsigned short*)(ws + 54611968);  //     65,536 -> 54,677,504
  // dead-region reuse (stream-ordered):
  float* partials = (float*)esrc;   // gemm1 partials [512][256] f32; esrc dead after k_agg
  float* ssbuf    = (float*)deg;    // 256 f32; deg dead (as cursor) after k_fill
  (void)ws_size; (void)in_sizes; (void)n_in; (void)out_size;

  k_zero  <<<98,   1024, 0, stream>>>(deg);
  k_setup <<<10000, 256, 0, stream>>>(x, Wl, Wr, ei, xbf, magg, wbf, deg);
  k_scan1 <<<NB,    256, 0, stream>>>(deg, bsum);
  k_scan3 <<<NB,    256, 0, stream>>>(deg, bsum, offs);
  k_fill  <<<2500,  256, 0, stream>>>(ei, deg, esrc);
  k_agg   <<<25000, 256, 0, stream>>>(offs, esrc, xbf, magg);
  k_gemm1 <<<GGRID, 512, 0, stream>>>(magg, xbf, wbf, partials);
  k_stats <<<1,    1024, 0, stream>>>(partials, bl, gamma, beta, ssbuf);
  k_norm  <<<GGRID, 512, 0, stream>>>(magg, ssbuf, out);
}

// Round 20
// 146.737 us; speedup vs baseline: 1.3608x; 1.0423x over previous
//
#include <hip/hip_runtime.h>
#include <stdint.h>

#define NN 100000     // nodes
#define NE 640000     // edges
#define DD 128        // features
#define BN_EPS 1e-5f
#define NB 391        // scan blocks: 391*256 = 100096 >= NN
#define NROWPAD 100096
#define NTILE 782     // 128-row tiles: 782*128 = 100096
#define GGRID 512     // gemm grid (2 blocks/CU)

typedef __attribute__((ext_vector_type(8)))  short bf16x8;
typedef __attribute__((ext_vector_type(4)))  float f32x4;

static __device__ __forceinline__ float bf2f(unsigned short s) {
  return __uint_as_float(((unsigned)s) << 16);
}
static __device__ __forceinline__ unsigned short f2bf(float f) {
  unsigned u = __float_as_uint(f);
  u += 0x7FFFu + ((u >> 16) & 1u);   // RNE
  return (unsigned short)(u >> 16);
}

// LAYOUT (R16/R17 proven):
//   magg[NROWPAD][128] bf16 : mean-agg; gemm overwrites in-place w/ out_pre.
//   xbf [NROWPAD][128] bf16 : relu(x), compact gather source.
// SCAN LEDGER (R14/R15/R18): the scan stays TWO launches. Merged variants
// either race (cursor writes into deg while others prefix-read it -> OOB
// crash) or go latency-bound (prefix over 400KB deg at 1KB stride = 54us,
// R18). The bsum materialization is what makes the prefix both cheap
// (391 L1-resident ints) and race-free. Do not re-merge.

// ---- 0. zero deg ---------------------------------------------------------
__global__ __launch_bounds__(1024) void k_zero(int* __restrict__ deg)
{
  int i = blockIdx.x * 1024 + threadIdx.x;
  if (i < NROWPAD) deg[i] = 0;
}

// ---- 1. merged setup, INTERLEAVED roles ----------------------------------
// hist blocks (640K device-scope atomics) are every 4th block (b&3==3 ->
// exactly 2500), spread uniformly so atomics overlap the prep streaming
// from t=0 (worth ~8us vs sequential role ranges).
__global__ __launch_bounds__(256) void k_setup(
    const float* __restrict__ x,
    const float* __restrict__ Wl, const float* __restrict__ Wr,
    const int* __restrict__ ei,
    unsigned short* __restrict__ xbf, unsigned short* __restrict__ magg,
    unsigned short* __restrict__ wbf, int* __restrict__ deg)
{
  int b = blockIdx.x;                   // grid 10000
  if ((b & 3) == 3) {
    int e = (b >> 2) * 256 + threadIdx.x;
    if (e < NE) atomicAdd(deg + ei[NE + e], 1);
    return;
  }
  int rank = b - (b >> 2);              // 0..7499
  if (rank < 6256) {
    // xbf[row][j] = bf16(relu(x[row][j])); pad rows zero xbf AND magg
    int i = rank * 256 + threadIdx.x;   // 0 .. NROWPAD*16-1
    int row = i >> 4, cj = i & 15;
    if (row < NN) {
      const float* xp = x + (long)row * DD + cj * 8;
      float tmp[8];
      *(float4*)(tmp)     = *(const float4*)(xp);
      *(float4*)(tmp + 4) = *(const float4*)(xp + 4);
      bf16x8 o;
#pragma unroll
      for (int e = 0; e < 8; ++e) o[e] = (short)f2bf(fmaxf(tmp[e], 0.f));
      *(bf16x8*)(xbf + (long)row * DD + cj * 8) = o;
    } else {                            // rows NN..NROWPAD-1: zero fill
      bf16x8 z = {};
      *(bf16x8*)(xbf  + (long)row * DD + cj * 8) = z;
      *(bf16x8*)(magg + (long)row * DD + cj * 8) = z;
    }
  } else if (rank < 6384) {
    // wbf[col][0..255] = [Wl[col][:] | Wr[col][:]] as bf16
    int i = (rank - 6256) * 256 + threadIdx.x;
    int col = i >> 8, k = i & 255;
    float v = (k < DD) ? Wl[col * DD + k] : Wr[col * DD + (k - DD)];
    wbf[i] = f2bf(v);
  }
}

// ---- 2a. block sums ------------------------------------------------------
__global__ __launch_bounds__(256) void k_scan1(const int* __restrict__ deg,
                                               int* __restrict__ bsum)
{
  __shared__ int sc[256];
  int t = threadIdx.x;
  sc[t] = deg[blockIdx.x * 256 + t];
  __syncthreads();
  for (int s = 128; s > 0; s >>= 1) {
    if (t < s) sc[t] += sc[t + s];
    __syncthreads();
  }
  if (t == 0) bsum[blockIdx.x] = sc[0];
}

// ---- 2b. per-element exclusive scan (self-computes block prefix from
// STABLE bsum; reads/writes only its OWN deg block -> race-free) ----------
__global__ __launch_bounds__(256) void k_scan3(int* __restrict__ deg,
                                               const int* __restrict__ bsum,
                                               int* __restrict__ offs)
{
  __shared__ int sc[256];
  __shared__ int pre[256];
  int t = threadIdx.x;
  int p = 0;
  for (int j = t; j < blockIdx.x; j += 256) p += bsum[j];
  pre[t] = p;
  __syncthreads();
  for (int s = 128; s > 0; s >>= 1) {
    if (t < s) pre[t] += pre[t + s];
    __syncthreads();
  }
  int boff = pre[0];
  __syncthreads();
  int i = blockIdx.x * 256 + t;
  int v = deg[i];
  sc[t] = v;
  __syncthreads();
  for (int s = 1; s < 256; s <<= 1) {
    int add = (t >= s) ? sc[t - s] : 0;
    __syncthreads();
    sc[t] += add;
    __syncthreads();
  }
  int excl = sc[t] - v + boff;
  offs[i] = excl;
  deg[i]  = excl;     // deg becomes fill-cursor
}

// ---- 3. fill CSR ---------------------------------------------------------
__global__ __launch_bounds__(256) void k_fill(const int* __restrict__ ei,
                                              int* __restrict__ cursor,
                                              int* __restrict__ esrc)
{
  int e = blockIdx.x * 256 + threadIdx.x;
  if (e >= NE) return;
  int pos = atomicAdd(cursor + ei[NE + e], 1);
  esrc[pos] = ei[e];
}

// ---- 4. gather-aggregate: magg[dst] = bf16(mean(xbf[src])) ---------------
// R19: each wave processes TWO dsts concurrently (2 independent load
// chains -> 2x MLP, 4 loads in flight with unroll 2) WITHOUT adding
// per-node VALU (two acc[8] 2-stage reduces per wave, half the waves --
// unlike R9's acc[16]/3-stage which tripled per-node reduce work).
// 4x16 quarter-wave layout per dst stream. Exhausted streams load the
// zeroed pad row (L1-hot, adds 0) -- branch-free.
__global__ __launch_bounds__(256) void k_agg(const int* __restrict__ offs,
                                             const int* __restrict__ esrc,
                                             const unsigned short* __restrict__ xbf,
                                             unsigned short* __restrict__ magg)
{
  int wv = threadIdx.x >> 6;
  int dst0 = blockIdx.x * 8 + wv * 2;   // grid 12500 -> dst0 max 99998
  int dst1 = dst0 + 1;
  int lane = threadIdx.x & 63;
  int q  = lane >> 4;        // quarter-wave 0..3 = edge slot
  int fl = lane & 15;        // feature lane: feats fl*8 .. fl*8+7
  int off0 = offs[dst0], end0 = offs[dst0 + 1];
  int off1 = offs[dst1], end1 = offs[dst1 + 1];   // dst1+1 <= 100000 < NROWPAD
  int deg0 = end0 - off0, deg1 = end1 - off1;
  float a0[8], a1[8];
#pragma unroll
  for (int e = 0; e < 8; ++e) { a0[e] = 0.f; a1[e] = 0.f; }

  int base0 = off0, base1 = off1;
  while (base0 < end0 || base1 < end1) {
    int m0 = end0 - base0; m0 = m0 < 0 ? 0 : (m0 > 64 ? 64 : m0);
    int m1 = end1 - base1; m1 = m1 < 0 ? 0 : (m1 > 64 ? 64 : m1);
    int mysrc0 = (base0 + lane < end0) ? esrc[base0 + lane] : NN;  // NN = zero pad row
    int mysrc1 = (base1 + lane < end1) ? esrc[base1 + lane] : NN;
    int mm = m0 > m1 ? m0 : m1;
    int iters = (mm + 3) >> 2;
#pragma unroll 2
    for (int i = 0; i < iters; ++i) {
      int s0 = __shfl(mysrc0, i * 4 + q);    // lanes >= m hold NN -> zero row
      int s1 = __shfl(mysrc1, i * 4 + q);
      bf16x8 w0 = *(const bf16x8*)(xbf + (long)s0 * DD + fl * 8);
      bf16x8 w1 = *(const bf16x8*)(xbf + (long)s1 * DD + fl * 8);
#pragma unroll
      for (int e = 0; e < 8; ++e) a0[e] += bf2f((unsigned short)w0[e]);
#pragma unroll
      for (int e = 0; e < 8; ++e) a1[e] += bf2f((unsigned short)w1[e]);
    }
    base0 += 64; base1 += 64;
  }

#pragma unroll
  for (int e = 0; e < 8; ++e) {
    a0[e] += __shfl_xor(a0[e], 16);
    a0[e] += __shfl_xor(a0[e], 32);
    a1[e] += __shfl_xor(a1[e], 16);
    a1[e] += __shfl_xor(a1[e], 32);
  }
  if (q == 0) {
    if (dst0 < NN) {
      float r0 = (deg0 > 0) ? 1.0f / (float)deg0 : 0.f;
      bf16x8 o;
#pragma unroll
      for (int e = 0; e < 8; ++e) o[e] = (short)f2bf(a0[e] * r0);
      *(bf16x8*)(magg + (long)dst0 * DD + fl * 8) = o;
    }
    if (dst1 < NN) {
      float r1 = (deg1 > 0) ? 1.0f / (float)deg1 : 0.f;
      bf16x8 o;
#pragma unroll
      for (int e = 0; e < 8; ++e) o[e] = (short)f2bf(a1[e] * r1);
      *(bf16x8*)(magg + (long)dst1 * DD + fl * 8) = o;
    }
  }
}

// ======== streaming GEMM (single pass) ====================================
// Block: 512 thr = 8 waves. B (= wbf, 128x256 bf16 = 64KB) staged once in
// LDS with XOR-swizzle byte ^= (col&7)<<4. Each wave owns a 16-row strip
// per tile; A-fragments load DIRECTLY from global: K 0..127 from magg row,
// K 128..255 from xbf row. No barriers in the tile loop.
// REGISTER BUDGET: (512,2) caps VGPR at 128 (2 blocks/CU, LDS-bound); per-
// ks A-load unroll 4, <=4 frags in flight -> no spills.
// LDS BUDGET: blds is EXACTLY 64KB -- do not add __shared__ variables.
#define GEMM_STAGE_B() \
  _Pragma("unroll") \
  for (int j = 0; j < 8; ++j) { \
    int id = j * 512 + t, col = id >> 5, seg = id & 31; \
    uint4 v = *(const uint4*)(wbf + col * 256 + seg * 8); \
    int byte = (col << 9) + (seg << 4); byte ^= (col & 7) << 4; \
    *(uint4*)((char*)blds + byte) = v; \
  } \
  __syncthreads();

#define GEMM_TILE_COMPUTE(rb) \
  { const unsigned short* ap0 = magg + (long)((rb) + c15) * DD + kg * 8; \
    const unsigned short* ap1 = xbf  + (long)((rb) + c15) * DD + kg * 8; \
    _Pragma("unroll 4") \
    for (int ks = 0; ks < 8; ++ks) { \
      bf16x8 a = (ks < 4) ? *(const bf16x8*)(ap0 + ks * 32) \
                          : *(const bf16x8*)(ap1 + (ks - 4) * 32); \
      _Pragma("unroll") \
      for (int ct = 0; ct < 8; ++ct) { \
        int byte = ((ct * 16 + c15) << 9) + (ks << 6) + (kg << 4); \
        byte ^= (c15 & 7) << 4; \
        bf16x8 b = *(const bf16x8*)((const char*)blds + byte); \
        acc[ct] = __builtin_amdgcn_mfma_f32_16x16x32_bf16(a, b, acc[ct], 0, 0, 0); \
      } \
    } }

// ---- 5. GEMM: raw column stats + bf16 out_pre OVER magg ------------------
// Pad rows are zeroed in xbf+magg -> contribute 0 to stats, store 0s.
__global__ __launch_bounds__(512, 2) void k_gemm1(
    unsigned short* __restrict__ magg,
    const unsigned short* __restrict__ xbf,
    const unsigned short* __restrict__ wbf,
    float* __restrict__ partials)
{
  __shared__ __align__(16) unsigned short blds[32768];   // 64KB B (FULL)
  const int t = threadIdx.x;
  const int lane = t & 63, wv = t >> 6;
  const int c15 = lane & 15, kg = lane >> 4;

  GEMM_STAGE_B();

  float sS[8], sQ[8];
#pragma unroll
  for (int ct = 0; ct < 8; ++ct) { sS[ct] = 0.f; sQ[ct] = 0.f; }

  for (int tile = blockIdx.x; tile < NTILE; tile += GGRID) {
    int rb = tile * 128 + wv * 16;
    f32x4 acc[8];
#pragma unroll
    for (int ct = 0; ct < 8; ++ct) acc[ct] = (f32x4){0.f, 0.f, 0.f, 0.f};
    GEMM_TILE_COMPUTE(rb);
#pragma unroll
    for (int ct = 0; ct < 8; ++ct) {
      int col = ct * 16 + c15;
#pragma unroll
      for (int r = 0; r < 4; ++r) {
        float v = acc[ct][r];
        sS[ct] += v;
        sQ[ct] += v * v;
        magg[(long)(rb + kg * 4 + r) * DD + col] = f2bf(v);  // out_pre bf16
      }
    }
  }

  // block-level reduce through LDS (B no longer needed)
  __syncthreads();
  float* slds = (float*)blds;   // [8 waves][256] = 8KB
#pragma unroll
  for (int ct = 0; ct < 8; ++ct) {
    float s = sS[ct], q = sQ[ct];
    s += __shfl_xor(s, 16); q += __shfl_xor(q, 16);
    s += __shfl_xor(s, 32); q += __shfl_xor(q, 32);
    if (lane < 16) {
      slds[wv * 256 + ct * 16 + lane] = s;
      slds[wv * 256 + 128 + ct * 16 + lane] = q;
    }
  }
  __syncthreads();
  if (t < 256) {
    float a = 0.f;
#pragma unroll
    for (int w = 0; w < 8; ++w) a += slds[w * 256 + t];
    partials[blockIdx.x * 256 + t] = a;
  }
}

// ---- 6. reduce partials; fold bias; emit sc / (bias*sc + shift) ----------
__global__ __launch_bounds__(1024) void k_stats(
    const float* __restrict__ partials, const float* __restrict__ bl,
    const float* __restrict__ gamma, const float* __restrict__ beta,
    float* __restrict__ ss)
{
  __shared__ float red[4][256];
  int t = threadIdx.x & 255, g = threadIdx.x >> 8;
  float a = 0.f;
#pragma unroll 8
  for (int blk = g; blk < GGRID; blk += 4) a += partials[blk * 256 + t];
  red[g][t] = a;
  __syncthreads();
  if (threadIdx.x < 256)
    red[0][t] = red[0][t] + red[1][t] + red[2][t] + red[3][t];
  __syncthreads();
  if (threadIdx.x < 128) {
    float Sr = red[0][t], Qr = red[0][128 + t];
    float b  = bl[t];
    float S  = Sr + (float)NN * b;                    // fold bias into stats
    float Q  = Qr + 2.f * b * Sr + (float)NN * b * b;
    float mu  = S / (float)NN;
    float var = Q / (float)NN - mu * mu;              // biased variance
    float rsig = rsqrtf(var + BN_EPS);
    float sc  = gamma[t] * rsig;
    float sh2 = beta[t] - mu * sc;
    ss[t]       = sc;
    ss[128 + t] = b * sc + sh2;                       // bias folded into shift
  }
}

// ---- 7. streaming BN affine: out = sc * out_pre(bf16) + shift ------------
// Grid geometry MATCHES k_gemm1 (512 blocks, tile = bid + 512-stride) so
// block b re-reads the out_pre rows gemm block b wrote (XCD-L2 locality
// heuristic; speed only, never correctness).
__global__ __launch_bounds__(512) void k_norm(
    const unsigned short* __restrict__ magg,
    const float* __restrict__ ss,
    float* __restrict__ out)
{
  __shared__ float sc[128], sh[128];
  if (threadIdx.x < 128) {
    sc[threadIdx.x] = ss[threadIdx.x];
    sh[threadIdx.x] = ss[128 + threadIdx.x];
  }
  __syncthreads();
  for (int tile = blockIdx.x; tile < NTILE; tile += GGRID) {
    long tb = (long)tile * 128;
    for (int i = threadIdx.x; i < 2048; i += 512) {   // 128 rows x 16 chunks
      long row = tb + (i >> 4);
      if (row >= NN) continue;
      int c0 = (i & 15) * 8;
      bf16x8 v = *(const bf16x8*)(magg + row * DD + c0);
      float4 o0, o1;
      o0.x = fmaf(bf2f((unsigned short)v[0]), sc[c0 + 0], sh[c0 + 0]);
      o0.y = fmaf(bf2f((unsigned short)v[1]), sc[c0 + 1], sh[c0 + 1]);
      o0.z = fmaf(bf2f((unsigned short)v[2]), sc[c0 + 2], sh[c0 + 2]);
      o0.w = fmaf(bf2f((unsigned short)v[3]), sc[c0 + 3], sh[c0 + 3]);
      o1.x = fmaf(bf2f((unsigned short)v[4]), sc[c0 + 4], sh[c0 + 4]);
      o1.y = fmaf(bf2f((unsigned short)v[5]), sc[c0 + 5], sh[c0 + 5]);
      o1.z = fmaf(bf2f((unsigned short)v[6]), sc[c0 + 6], sh[c0 + 6]);
      o1.w = fmaf(bf2f((unsigned short)v[7]), sc[c0 + 7], sh[c0 + 7]);
      *(float4*)(out + row * DD + c0)     = o0;
      *(float4*)(out + row * DD + c0 + 4) = o1;
    }
  }
}

extern "C" void kernel_launch(void* const* d_in, const int* in_sizes, int n_in,
                              void* d_out, int out_size, void* d_ws, size_t ws_size,
                              hipStream_t stream)
{
  const float* x     = (const float*)d_in[0];
  // d_in[1] = edge_attr — unused by the reference
  const float* Wl    = (const float*)d_in[2];
  const float* bl    = (const float*)d_in[3];
  const float* Wr    = (const float*)d_in[4];
  const float* gamma = (const float*)d_in[5];
  const float* beta  = (const float*)d_in[6];
  const int*   ei    = (const int*)d_in[7];
  float* out = (float*)d_out;

  char* ws = (char*)d_ws;
  unsigned short* magg = (unsigned short*)(ws);            // 100096*128*2 = 25,624,576
  unsigned short* xbf  = (unsigned short*)(ws + 25624576); // 25,624,576 -> 51,249,152
  int*   esrc  = (int*)(ws + 51249152);                    //  2,560,000 -> 53,809,152
  int*   deg   = (int*)(ws + 53809152);                    //    400,384 -> 54,209,536
  int*   offs  = (int*)(ws + 54209536);                    //    400,384 -> 54,609,920
  int*   bsum  = (int*)(ws + 54609920);                    //      2,048 -> 54,611,968
  unsigned short* wbf = (unsigned short*)(ws + 54611968);  //     65,536 -> 54,677,504
  // dead-region reuse (stream-ordered):
  float* partials = (float*)esrc;   // gemm1 partials [512][256] f32; esrc dead after k_agg
  float* ssbuf    = (float*)deg;    // 256 f32; deg dead (as cursor) after k_fill
  (void)ws_size; (void)in_sizes; (void)n_in; (void)out_size;

  k_zero  <<<98,   1024, 0, stream>>>(deg);
  k_setup <<<10000, 256, 0, stream>>>(x, Wl, Wr, ei, xbf, magg, wbf, deg);
  k_scan1 <<<NB,    256, 0, stream>>>(deg, bsum);
  k_scan3 <<<NB,    256, 0, stream>>>(deg, bsum, offs);
  k_fill  <<<2500,  256, 0, stream>>>(ei, deg, esrc);
  k_agg   <<<12500, 256, 0, stream>>>(offs, esrc, xbf, magg);
  k_gemm1 <<<GGRID, 512, 0, stream>>>(magg, xbf, wbf, partials);
  k_stats <<<1,    1024, 0, stream>>>(partials, bl, gamma, beta, ssbuf);
  k_norm  <<<GGRID, 512, 0, stream>>>(magg, ssbuf, out);
}